// Round 4
// baseline (114.491 us; speedup 1.0000x reference)
//
#include <hip/hip_runtime.h>
#include <math.h>

// Round 4 resubmission (rounds 1-3 hit UnresponsiveContainer infra failures).
// Problem constants (from reference):
//   x: [128,128,128,16] f32
//   MaxPool3d window 4, stride 2, VALID -> pooled [63,63,63,16]
//   patches: 30x30x30 cubes of 4x4x4 at stride 2 -> out (27000, 64, 16) f32
#define D0 128          // input spatial edge
#define NC 16           // channels
#define DP 63           // pooled spatial edge
#define NPATCH 30       // patches per axis
#define POOL_THREADS (DP*DP*DP*4)          // one thread per (dp,hp,wp, c-quad)
#define OUT_THREADS  (NPATCH*NPATCH*NPATCH*64*4)  // one thread per out float4

__global__ void pool_kernel(const float* __restrict__ x, float* __restrict__ pooled) {
    const int stride = gridDim.x * blockDim.x;
    for (int tid = blockIdx.x * blockDim.x + threadIdx.x; tid < POOL_THREADS; tid += stride) {
        const int c4 = tid & 3;
        int rest = tid >> 2;
        const int wp = rest % DP; rest /= DP;
        const int hp = rest % DP;
        const int dp = rest / DP;

        float4 m = make_float4(-INFINITY, -INFINITY, -INFINITY, -INFINITY);
        // base x position (2dp, 2hp, 2wp)
        const int xpos0 = ((dp * 2) * D0 + hp * 2) * D0 + wp * 2;
        for (int u = 0; u < 4; ++u) {
            for (int v = 0; v < 4; ++v) {
                const int rowpos = xpos0 + (u * D0 + v) * D0;
#pragma unroll
                for (int w = 0; w < 4; ++w) {
                    const float4 val = *reinterpret_cast<const float4*>(
                        &x[(size_t)(rowpos + w) * NC + c4 * 4]);
                    m.x = fmaxf(m.x, val.x);
                    m.y = fmaxf(m.y, val.y);
                    m.z = fmaxf(m.z, val.z);
                    m.w = fmaxf(m.w, val.w);
                }
            }
        }
        // pooled flat layout [dp][hp][wp][c]: flat float index == tid*4
        *reinterpret_cast<float4*>(&pooled[(size_t)tid * 4]) = m;
    }
}

__global__ void gather_kernel(const float* __restrict__ pooled, float* __restrict__ out) {
    const int stride = gridDim.x * blockDim.x;
    for (int tid = blockIdx.x * blockDim.x + threadIdx.x; tid < OUT_THREADS; tid += stride) {
        const int c4 = tid & 3;
        const int w = (tid >> 2) & 63;     // (a*4+b)*4+cc
        const int n = tid >> 8;            // patch index (i*30+j)*30+k
        const int cc = w & 3;
        const int b = (w >> 2) & 3;
        const int a = w >> 4;
        const int k = n % NPATCH;
        const int t = n / NPATCH;
        const int j = t % NPATCH;
        const int i = t / NPATCH;
        const int dp = i * 2 + a;
        const int hp = j * 2 + b;
        const int wp = k * 2 + cc;
        const int src = ((dp * DP + hp) * DP + wp) * 4 + c4;  // float4 index
        const float4 v = *reinterpret_cast<const float4*>(&pooled[(size_t)src * 4]);
        *reinterpret_cast<float4*>(&out[(size_t)tid * 4]) = v;  // out flat == tid*4
    }
}

// Fallback if workspace too small: recompute the 64-way max per output element.
__global__ void fused_kernel(const float* __restrict__ x, float* __restrict__ out) {
    const int stride = gridDim.x * blockDim.x;
    for (int tid = blockIdx.x * blockDim.x + threadIdx.x; tid < OUT_THREADS; tid += stride) {
        const int c4 = tid & 3;
        const int w = (tid >> 2) & 63;
        const int n = tid >> 8;
        const int cc = w & 3;
        const int b = (w >> 2) & 3;
        const int a = w >> 4;
        const int k = n % NPATCH;
        const int t = n / NPATCH;
        const int j = t % NPATCH;
        const int i = t / NPATCH;
        const int dp = i * 2 + a;
        const int hp = j * 2 + b;
        const int wp = k * 2 + cc;

        float4 m = make_float4(-INFINITY, -INFINITY, -INFINITY, -INFINITY);
        const int xpos0 = ((dp * 2) * D0 + hp * 2) * D0 + wp * 2;
        for (int u = 0; u < 4; ++u) {
            for (int v = 0; v < 4; ++v) {
                const int rowpos = xpos0 + (u * D0 + v) * D0;
#pragma unroll
                for (int ww = 0; ww < 4; ++ww) {
                    const float4 val = *reinterpret_cast<const float4*>(
                        &x[(size_t)(rowpos + ww) * NC + c4 * 4]);
                    m.x = fmaxf(m.x, val.x);
                    m.y = fmaxf(m.y, val.y);
                    m.z = fmaxf(m.z, val.z);
                    m.w = fmaxf(m.w, val.w);
                }
            }
        }
        *reinterpret_cast<float4*>(&out[(size_t)tid * 4]) = m;
    }
}

extern "C" void kernel_launch(void* const* d_in, const int* in_sizes, int n_in,
                              void* d_out, int out_size, void* d_ws, size_t ws_size,
                              hipStream_t stream) {
    const float* x = (const float*)d_in[0];
    float* out = (float*)d_out;

    const size_t pooled_bytes = (size_t)DP * DP * DP * NC * sizeof(float);
    const int threads = 256;

    if (ws_size >= pooled_bytes) {
        float* pooled = (float*)d_ws;
        int blocks1 = (POOL_THREADS + threads - 1) / threads;
        if (blocks1 > 2048) blocks1 = 2048;
        pool_kernel<<<blocks1, threads, 0, stream>>>(x, pooled);

        int blocks2 = (OUT_THREADS + threads - 1) / threads;
        if (blocks2 > 2048) blocks2 = 2048;
        gather_kernel<<<blocks2, threads, 0, stream>>>(pooled, out);
    } else {
        int blocks = (OUT_THREADS + threads - 1) / threads;
        if (blocks > 2048) blocks = 2048;
        fused_kernel<<<blocks, threads, 0, stream>>>(x, out);
    }
}

// Round 6
// 88.215 us; speedup vs baseline: 1.2979x; 1.2979x over previous
//
#include <hip/hip_runtime.h>
#include <math.h>

// x: [128,128,128,16] f32 ; MaxPool3d win 4 stride 2 -> pooled [63,63,63,16]
// patches: 30^3 cubes of 4^3 at stride 2 -> out (27000, 64, 16) f32
#define D0 128
#define NC 16
#define DP 63
#define NPATCH 30
#define DCH 7                      // dp outputs per thread (rolling-d chunk)
#define NCHUNK 9                   // 9*7 = 63 exact
#define POOL2_THREADS (NCHUNK*DP*DP*4)            // thread per (chunk,hp,wp,c4)
#define OUT_THREADS  (NPATCH*NPATCH*NPATCH*64*4)  // thread per out float4

typedef float f32x4 __attribute__((ext_vector_type(4)));  // native vec for NT store

__device__ __forceinline__ float4 f4max(float4 a, float4 b) {
    return make_float4(fmaxf(a.x, b.x), fmaxf(a.y, b.y), fmaxf(a.z, b.z), fmaxf(a.w, b.w));
}

// Rolling-d pool: each thread computes DCH consecutive dp outputs for a fixed
// (hp, wp, c4) column. Each x d-row is fetched once per chunk (16 rows / 14-row
// stride = 1.14x), eliminating the 2x dp-overlap HBM refetch of v1.
__global__ void pool_kernel(const float* __restrict__ x, float* __restrict__ pooled) {
    const int tid = blockIdx.x * blockDim.x + threadIdx.x;
    if (tid >= POOL2_THREADS) return;
    const int c4 = tid & 3;
    int rest = tid >> 2;
    const int wp = rest % DP; rest /= DP;
    const int hp = rest % DP;
    const int chunk = rest / DP;       // 0..8
    const int dp0 = chunk * DCH;       // first dp of this chunk

    // hw[ld] = max over 4x4 (h,w) window at d-row 2*dp0+ld
    float4 hw[2 * DCH + 2];            // 16 rows
    const int hwbase = (hp * 2) * D0 + wp * 2;   // (h,w) base within a d-slice
#pragma unroll
    for (int ld = 0; ld < 2 * DCH + 2; ++ld) {
        const int d = 2 * dp0 + ld;
        const size_t dbase = (size_t)d * D0 * D0 + hwbase;
        float4 m = make_float4(-INFINITY, -INFINITY, -INFINITY, -INFINITY);
#pragma unroll
        for (int v = 0; v < 4; ++v) {
#pragma unroll
            for (int w = 0; w < 4; ++w) {
                const float4 val = *reinterpret_cast<const float4*>(
                    &x[(dbase + v * D0 + w) * NC + c4 * 4]);
                m = f4max(m, val);
            }
        }
        hw[ld] = m;
    }
#pragma unroll
    for (int i = 0; i < DCH; ++i) {
        const int dp = dp0 + i;
        const float4 r = f4max(f4max(hw[2 * i], hw[2 * i + 1]),
                               f4max(hw[2 * i + 2], hw[2 * i + 3]));
        // lanes (c4 fastest, wp next) -> contiguous 1KB per wave store
        *reinterpret_cast<float4*>(&pooled[(size_t)(((dp * DP + hp) * DP + wp) * 4 + c4) * 4]) = r;
    }
}

__global__ void gather_kernel(const float* __restrict__ pooled, float* __restrict__ out) {
    const int stride = gridDim.x * blockDim.x;
    for (int tid = blockIdx.x * blockDim.x + threadIdx.x; tid < OUT_THREADS; tid += stride) {
        const int c4 = tid & 3;
        const int w = (tid >> 2) & 63;     // (a*4+b)*4+cc
        const int n = tid >> 8;            // patch index (i*30+j)*30+k
        const int cc = w & 3;
        const int b = (w >> 2) & 3;
        const int a = w >> 4;
        const int k = n % NPATCH;
        const int t = n / NPATCH;
        const int j = t % NPATCH;
        const int i = t / NPATCH;
        const int dp = i * 2 + a;
        const int hp = j * 2 + b;
        const int wp = k * 2 + cc;
        const int src = ((dp * DP + hp) * DP + wp) * 4 + c4;  // float4 index
        const f32x4 v = *reinterpret_cast<const f32x4*>(&pooled[(size_t)src * 4]);
        // write-once stream: nontemporal, out flat float4 index == tid
        __builtin_nontemporal_store(v, reinterpret_cast<f32x4*>(&out[(size_t)tid * 4]));
    }
}

// Fallback if workspace too small: recompute the 64-way max per output element.
__global__ void fused_kernel(const float* __restrict__ x, float* __restrict__ out) {
    const int stride = gridDim.x * blockDim.x;
    for (int tid = blockIdx.x * blockDim.x + threadIdx.x; tid < OUT_THREADS; tid += stride) {
        const int c4 = tid & 3;
        const int w = (tid >> 2) & 63;
        const int n = tid >> 8;
        const int cc = w & 3;
        const int b = (w >> 2) & 3;
        const int a = w >> 4;
        const int k = n % NPATCH;
        const int t = n / NPATCH;
        const int j = t % NPATCH;
        const int i = t / NPATCH;
        const int dp = i * 2 + a;
        const int hp = j * 2 + b;
        const int wp = k * 2 + cc;
        float4 m = make_float4(-INFINITY, -INFINITY, -INFINITY, -INFINITY);
        const int xpos0 = ((dp * 2) * D0 + hp * 2) * D0 + wp * 2;
        for (int u = 0; u < 4; ++u)
            for (int v = 0; v < 4; ++v) {
                const int rowpos = xpos0 + (u * D0 + v) * D0;
#pragma unroll
                for (int ww = 0; ww < 4; ++ww) {
                    const float4 val = *reinterpret_cast<const float4*>(
                        &x[(size_t)(rowpos + ww) * NC + c4 * 4]);
                    m = f4max(m, val);
                }
            }
        *reinterpret_cast<float4*>(&out[(size_t)tid * 4]) = m;
    }
}

extern "C" void kernel_launch(void* const* d_in, const int* in_sizes, int n_in,
                              void* d_out, int out_size, void* d_ws, size_t ws_size,
                              hipStream_t stream) {
    const float* x = (const float*)d_in[0];
    float* out = (float*)d_out;

    const size_t pooled_bytes = (size_t)DP * DP * DP * NC * sizeof(float);
    const int threads = 256;

    if (ws_size >= pooled_bytes) {
        float* pooled = (float*)d_ws;
        const int blocks1 = (POOL2_THREADS + threads - 1) / threads;  // 559
        pool_kernel<<<blocks1, threads, 0, stream>>>(x, pooled);

        int blocks2 = (OUT_THREADS + threads - 1) / threads;
        if (blocks2 > 2048) blocks2 = 2048;
        gather_kernel<<<blocks2, threads, 0, stream>>>(pooled, out);
    } else {
        int blocks = (OUT_THREADS + threads - 1) / threads;
        if (blocks > 2048) blocks = 2048;
        fused_kernel<<<blocks, threads, 0, stream>>>(x, out);
    }
}